// Round 1
// baseline (714.509 us; speedup 1.0000x reference)
//
#include <hip/hip_runtime.h>

// ---------------------------------------------------------------------------
// ConvRNN GCN cell, f32 correctness-first implementation.
// Pipeline:
//   0. zero degcnt/cursor
//   1. detect edge dtype (int32 vs int64) on device
//   2. decode edges -> int32, histogram in-degree (dst)
//   3. dinv = rsqrt(deg+1)   (+1 = self loop)
//   4. GEMM1: hs = ([x|hidden] @ W) * dinv[row]
//   5. prefix scan of degcnt -> CSR offsets
//   6. fill CSR (edge -> slot under its dst)
//   7. aggregate: nh = sigmoid(b + (sum_src hs[src] + hs[n]) * dinv[n] + bias)
//   8. GEMM2: o = c + nh @ V
// ---------------------------------------------------------------------------

__global__ void zero_u32_kernel(unsigned int* p, long long n) {
    long long i = (long long)blockIdx.x * blockDim.x + threadIdx.x;
    if (i < n) p[i] = 0u;
}

// flag = 1 if buffer is int64 (all sampled high words zero), else 0.
__global__ void detect_dtype_kernel(const unsigned int* e, int* flag) {
    __shared__ int nz;
    if (threadIdx.x == 0) nz = 0;
    __syncthreads();
    for (int i = threadIdx.x; i < 512; i += blockDim.x) {
        if (e[2 * i + 1] != 0u) nz = 1;
    }
    __syncthreads();
    if (threadIdx.x == 0) *flag = (nz == 0) ? 1 : 0;
}

__global__ void decode_edges_kernel(const void* eraw, int* edges32,
                                    unsigned int* degcnt,
                                    long long twoE, long long E, int N,
                                    const int* flag) {
    long long i = (long long)blockIdx.x * blockDim.x + threadIdx.x;
    if (i >= twoE) return;
    int is64 = *flag;
    int v;
    if (is64) v = (int)((const long long*)eraw)[i];
    else      v = ((const int*)eraw)[i];
    // memory-safety clamp (no-op for valid inputs)
    v = v < 0 ? 0 : (v >= N ? N - 1 : v);
    edges32[i] = v;
    if (i >= E) atomicAdd(&degcnt[v], 1u);   // dst half -> in-degree
}

__global__ void dinv_kernel(const unsigned int* degcnt, float* dinv, int N) {
    int n = blockIdx.x * blockDim.x + threadIdx.x;
    if (n < N) dinv[n] = rsqrtf((float)(degcnt[n] + 1u));
}

// GEMM1: hs[n][c] = (sum_k xh[n][k] * W[k][c]) * dinv[n]; xh = [x | hidden]
// Tile: 64 rows x 128 cols / block of 256 threads; thread = 4 rows x 8 cols.
__global__ __launch_bounds__(256) void gemm1_kernel(
    const float* __restrict__ x, const float* __restrict__ hidden,
    const float* __restrict__ W, const float* __restrict__ dinv,
    float* __restrict__ hs, int N)
{
    __shared__ __align__(16) float Wlds[128][128];  // one K-tile of W (64 KB)
    const int t  = threadIdx.x;
    const int cg = t & 15;
    const int rg = t >> 4;
    const int c0 = cg * 8;
    const int row0 = blockIdx.x * 64 + rg * 4;

    float acc[4][8];
#pragma unroll
    for (int i = 0; i < 4; ++i)
#pragma unroll
        for (int j = 0; j < 8; ++j) acc[i][j] = 0.f;

    for (int kt = 0; kt < 2; ++kt) {
        __syncthreads();
        {
            const float4* Wg = (const float4*)(W + (size_t)kt * 128 * 128);
            float4* Wl = (float4*)&Wlds[0][0];
            for (int idx = t; idx < 128 * 128 / 4; idx += 256) Wl[idx] = Wg[idx];
        }
        __syncthreads();
        const float* __restrict__ src = (kt == 0) ? x : hidden;

        for (int k = 0; k < 128; k += 4) {
            float4 xv4[4];
#pragma unroll
            for (int i = 0; i < 4; ++i) {
                int r = row0 + i;
                xv4[i] = (r < N) ? *(const float4*)&src[(size_t)r * 128 + k]
                                 : make_float4(0.f, 0.f, 0.f, 0.f);
            }
#pragma unroll
            for (int kk = 0; kk < 4; ++kk) {
                float4 wa = *(const float4*)&Wlds[k + kk][c0];
                float4 wb = *(const float4*)&Wlds[k + kk][c0 + 4];
                float w[8] = {wa.x, wa.y, wa.z, wa.w, wb.x, wb.y, wb.z, wb.w};
#pragma unroll
                for (int i = 0; i < 4; ++i) {
                    float xv = (kk == 0) ? xv4[i].x : (kk == 1) ? xv4[i].y
                             : (kk == 2) ? xv4[i].z : xv4[i].w;
#pragma unroll
                    for (int j = 0; j < 8; ++j) acc[i][j] += xv * w[j];
                }
            }
        }
    }

#pragma unroll
    for (int i = 0; i < 4; ++i) {
        int r = row0 + i;
        if (r < N) {
            float s = dinv[r];
            float4 o1 = make_float4(acc[i][0] * s, acc[i][1] * s,
                                    acc[i][2] * s, acc[i][3] * s);
            float4 o2 = make_float4(acc[i][4] * s, acc[i][5] * s,
                                    acc[i][6] * s, acc[i][7] * s);
            *(float4*)&hs[(size_t)r * 128 + c0]     = o1;
            *(float4*)&hs[(size_t)r * 128 + c0 + 4] = o2;
        }
    }
}

// --- prefix scan (3 kernels) ---
__global__ void scan_block_kernel(const unsigned int* degcnt, unsigned int* off,
                                  unsigned int* blocksum, int N) {
    __shared__ unsigned int s[256];
    int gid = blockIdx.x * 256 + threadIdx.x;
    unsigned int v = (gid < N) ? degcnt[gid] : 0u;
    s[threadIdx.x] = v;
    __syncthreads();
    for (int ofs = 1; ofs < 256; ofs <<= 1) {
        unsigned int tv = (threadIdx.x >= ofs) ? s[threadIdx.x - ofs] : 0u;
        __syncthreads();
        s[threadIdx.x] += tv;
        __syncthreads();
    }
    if (gid < N) off[gid] = s[threadIdx.x] - v;  // exclusive
    if (threadIdx.x == 255) blocksum[blockIdx.x] = s[255];
}

__global__ void scan_sums_kernel(unsigned int* blocksum, int nb) {
    __shared__ unsigned int s[1024];
    int tid = threadIdx.x;
    unsigned int v = (tid < nb) ? blocksum[tid] : 0u;
    s[tid] = v;
    __syncthreads();
    for (int ofs = 1; ofs < 1024; ofs <<= 1) {
        unsigned int tv = (tid >= ofs) ? s[tid - ofs] : 0u;
        __syncthreads();
        s[tid] += tv;
        __syncthreads();
    }
    if (tid < nb) blocksum[tid] = s[tid] - v;    // exclusive
}

__global__ void add_offsets_kernel(unsigned int* off, const unsigned int* blocksum, int N) {
    int gid = blockIdx.x * 256 + threadIdx.x;
    if (gid < N) off[gid] += blocksum[blockIdx.x];
}

__global__ void fill_csr_kernel(const int* __restrict__ edges32,
                                const unsigned int* __restrict__ off,
                                unsigned int* cursor, int* csr_src, long long E) {
    long long e = (long long)blockIdx.x * blockDim.x + threadIdx.x;
    if (e >= E) return;
    int s = edges32[e];
    int d = edges32[E + e];
    unsigned int pos = atomicAdd(&cursor[d], 1u);
    csr_src[off[d] + pos] = s;
}

// aggregate + self-loop + bias + b_matrix + sigmoid -> new_hidden (d_out)
__global__ __launch_bounds__(128) void aggregate_kernel(
    const float* __restrict__ hs, const int* __restrict__ csr_src,
    const unsigned int* __restrict__ off, const unsigned int* __restrict__ degcnt,
    const float* __restrict__ dinv, const float* __restrict__ bmat,
    const float* __restrict__ bias, float* __restrict__ out_nh, int N)
{
    __shared__ int slist[128];
    int n = blockIdx.x;
    int c = threadIdx.x;
    unsigned int start = off[n];
    unsigned int cnt   = degcnt[n];
    float acc = hs[(size_t)n * 128 + c];          // self loop (hs = h*dinv)
    for (unsigned int base = 0; base < cnt; base += 128) {
        unsigned int m = min(128u, cnt - base);
        __syncthreads();
        if ((unsigned)c < m) slist[c] = csr_src[start + base + c];
        __syncthreads();
        for (unsigned int i = 0; i < m; ++i)
            acc += hs[(size_t)slist[i] * 128 + c];
    }
    float conv = acc * dinv[n] + bias[c];
    float val  = bmat[(size_t)n * 128 + c] + conv;
    out_nh[(size_t)n * 128 + c] = 1.0f / (1.0f + __expf(-val));
}

// GEMM2: o[n][c] = c_matrix[n][c] + sum_h nh[n][h] * V[h][c]
__global__ __launch_bounds__(256) void gemm2_kernel(
    const float* __restrict__ nh, const float* __restrict__ V,
    const float* __restrict__ cmat, float* __restrict__ o, int N)
{
    __shared__ __align__(16) float Vlds[128][128];
    const int t  = threadIdx.x;
    const int cg = t & 15;
    const int rg = t >> 4;
    const int c0 = cg * 8;
    const int row0 = blockIdx.x * 64 + rg * 4;

    {
        const float4* Vg = (const float4*)V;
        float4* Vl = (float4*)&Vlds[0][0];
        for (int idx = t; idx < 128 * 128 / 4; idx += 256) Vl[idx] = Vg[idx];
    }
    __syncthreads();

    float acc[4][8];
#pragma unroll
    for (int i = 0; i < 4; ++i)
#pragma unroll
        for (int j = 0; j < 8; ++j) acc[i][j] = 0.f;

    for (int k = 0; k < 128; k += 4) {
        float4 xv4[4];
#pragma unroll
        for (int i = 0; i < 4; ++i) {
            int r = row0 + i;
            xv4[i] = (r < N) ? *(const float4*)&nh[(size_t)r * 128 + k]
                             : make_float4(0.f, 0.f, 0.f, 0.f);
        }
#pragma unroll
        for (int kk = 0; kk < 4; ++kk) {
            float4 wa = *(const float4*)&Vlds[k + kk][c0];
            float4 wb = *(const float4*)&Vlds[k + kk][c0 + 4];
            float w[8] = {wa.x, wa.y, wa.z, wa.w, wb.x, wb.y, wb.z, wb.w};
#pragma unroll
            for (int i = 0; i < 4; ++i) {
                float xv = (kk == 0) ? xv4[i].x : (kk == 1) ? xv4[i].y
                         : (kk == 2) ? xv4[i].z : xv4[i].w;
#pragma unroll
                for (int j = 0; j < 8; ++j) acc[i][j] += xv * w[j];
            }
        }
    }

#pragma unroll
    for (int i = 0; i < 4; ++i) {
        int r = row0 + i;
        if (r < N) {
            float4 ca = *(const float4*)&cmat[(size_t)r * 128 + c0];
            float4 cb = *(const float4*)&cmat[(size_t)r * 128 + c0 + 4];
            float4 o1 = make_float4(acc[i][0] + ca.x, acc[i][1] + ca.y,
                                    acc[i][2] + ca.z, acc[i][3] + ca.w);
            float4 o2 = make_float4(acc[i][4] + cb.x, acc[i][5] + cb.y,
                                    acc[i][6] + cb.z, acc[i][7] + cb.w);
            *(float4*)&o[(size_t)r * 128 + c0]     = o1;
            *(float4*)&o[(size_t)r * 128 + c0 + 4] = o2;
        }
    }
}

extern "C" void kernel_launch(void* const* d_in, const int* in_sizes, int n_in,
                              void* d_out, int out_size, void* d_ws, size_t ws_size,
                              hipStream_t stream) {
    const float* x      = (const float*)d_in[0];
    const float* hidden = (const float*)d_in[1];
    const float* W      = (const float*)d_in[2];
    const float* bias   = (const float*)d_in[3];
    const float* bmat   = (const float*)d_in[4];
    const float* V      = (const float*)d_in[5];
    const float* cmat   = (const float*)d_in[6];
    const void*  eraw   = d_in[7];

    const int H = in_sizes[3];                 // 128
    const int F = in_sizes[5] / H;             // 128
    const int N = in_sizes[0] / F;             // 100000
    const long long twoE = in_sizes[7];
    const long long E    = twoE / 2;

    // ---- workspace layout ----
    char* p = (char*)d_ws;
    int* flag = (int*)p;                        p += 256;
    unsigned int* degcnt = (unsigned int*)p;    p += (size_t)N * 4;
    unsigned int* cursor = (unsigned int*)p;    p += (size_t)N * 4;   // contiguous w/ degcnt
    unsigned int* off    = (unsigned int*)p;    p += (size_t)N * 4;
    float* dinv          = (float*)p;           p += (size_t)N * 4;
    unsigned int* blocksum = (unsigned int*)p;  p += 4096;
    int* edges32         = (int*)p;             p += (size_t)twoE * 4;
    int* csr_src         = (int*)p;             p += (size_t)E * 4;
    float* hs            = (float*)p;           p += (size_t)N * H * 4;

    float* out_o  = (float*)d_out;
    float* out_nh = (float*)d_out + (size_t)N * F;

    // 0. zero degcnt + cursor (contiguous, 2N words)
    {
        long long nz = 2LL * N;
        zero_u32_kernel<<<(unsigned)((nz + 255) / 256), 256, 0, stream>>>(degcnt, nz);
    }
    // 1. dtype detect
    detect_dtype_kernel<<<1, 256, 0, stream>>>((const unsigned int*)eraw, flag);
    // 2. decode + degree histogram
    decode_edges_kernel<<<(unsigned)((twoE + 255) / 256), 256, 0, stream>>>(
        eraw, edges32, degcnt, twoE, E, N, flag);
    // 3. dinv
    dinv_kernel<<<(N + 255) / 256, 256, 0, stream>>>(degcnt, dinv, N);
    // 4. GEMM1 (scaled by dinv)
    gemm1_kernel<<<(N + 63) / 64, 256, 0, stream>>>(x, hidden, W, dinv, hs, N);
    // 5. prefix scan -> off
    int nb = (N + 255) / 256;
    scan_block_kernel<<<nb, 256, 0, stream>>>(degcnt, off, blocksum, N);
    scan_sums_kernel<<<1, 1024, 0, stream>>>(blocksum, nb);
    add_offsets_kernel<<<nb, 256, 0, stream>>>(off, blocksum, N);
    // 6. fill CSR
    fill_csr_kernel<<<(unsigned)((E + 255) / 256), 256, 0, stream>>>(
        edges32, off, cursor, csr_src, E);
    // 7. aggregate + sigmoid -> new_hidden
    aggregate_kernel<<<N, 128, 0, stream>>>(hs, csr_src, off, degcnt, dinv,
                                            bmat, bias, out_nh, N);
    // 8. GEMM2 -> o
    gemm2_kernel<<<(N + 63) / 64, 256, 0, stream>>>(out_nh, V, cmat, out_o, N);
}

// Round 2
// 438.367 us; speedup vs baseline: 1.6299x; 1.6299x over previous
//
#include <hip/hip_runtime.h>

// ---------------------------------------------------------------------------
// ConvRNN GCN cell — bf16-MFMA GEMMs + CSR gather aggregation.
//   0. zero degcnt/cursor
//   1. detect edge dtype (int64 vs int32)
//   2. decode edges -> int32, in-degree histogram
//   3. dinv = rsqrt(deg+1)
//   4. Wt/Vt = bf16 transposed weights (for MFMA A-operand fragments)
//   5. GEMM1 (MFMA): hs16 = bf16(([x|hidden] @ W) * dinv[row])
//   6. prefix scan -> CSR offsets; fill CSR
//   7. aggregate (wave/node): nh = sigmoid(b + (sum hs16[src] + hs16[n])*dinv + bias)
//      -> out_nh (f32, d_out) and nh16 (bf16, ws)
//   8. GEMM2 (MFMA): o = cmat + nh16 @ V
// MFMA operand swap: mfma(A=Wt-frag, B=row-frag) => lane holds 4 consecutive
// output columns (row=(lane>>4)*4+reg indexes W-cols, col=lane&15 indexes rows).
// ---------------------------------------------------------------------------

typedef __attribute__((ext_vector_type(8))) short bf16x8;
typedef __attribute__((ext_vector_type(4))) short s16x4;
typedef __attribute__((ext_vector_type(4))) float f32x4;

__device__ __forceinline__ unsigned short f2bf(float f) {
    unsigned int u = __float_as_uint(f);
    unsigned int r = u + 0x7fffu + ((u >> 16) & 1u);   // round-to-nearest-even
    return (unsigned short)(r >> 16);
}
__device__ __forceinline__ float bflo(unsigned int u) { return __uint_as_float(u << 16); }
__device__ __forceinline__ float bfhi(unsigned int u) { return __uint_as_float(u & 0xffff0000u); }

__global__ void zero_u32_kernel(unsigned int* p, long long n) {
    long long i = (long long)blockIdx.x * blockDim.x + threadIdx.x;
    if (i < n) p[i] = 0u;
}

__global__ void detect_dtype_kernel(const unsigned int* e, int* flag) {
    __shared__ int nz;
    if (threadIdx.x == 0) nz = 0;
    __syncthreads();
    for (int i = threadIdx.x; i < 512; i += blockDim.x)
        if (e[2 * i + 1] != 0u) nz = 1;
    __syncthreads();
    if (threadIdx.x == 0) *flag = (nz == 0) ? 1 : 0;
}

__global__ void decode_edges_kernel(const void* eraw, int* edges32,
                                    unsigned int* degcnt,
                                    long long twoE, long long E, int N,
                                    const int* flag) {
    long long i = (long long)blockIdx.x * blockDim.x + threadIdx.x;
    if (i >= twoE) return;
    int v;
    if (*flag) v = (int)((const long long*)eraw)[i];
    else       v = ((const int*)eraw)[i];
    v = v < 0 ? 0 : (v >= N ? N - 1 : v);
    edges32[i] = v;
    if (i >= E) atomicAdd(&degcnt[v], 1u);   // dst half
}

__global__ void dinv_kernel(const unsigned int* degcnt, float* dinv, int N) {
    int n = blockIdx.x * blockDim.x + threadIdx.x;
    if (n < N) dinv[n] = rsqrtf((float)(degcnt[n] + 1u));
}

// Wt[c][k] = bf16(W[k][c])  (128 x 256);  Vt[c][k] = bf16(V[k][c])  (128 x 128)
__global__ void prep_wt_kernel(const float* __restrict__ W, const float* __restrict__ V,
                               unsigned short* __restrict__ Wt, unsigned short* __restrict__ Vt) {
    int idx = blockIdx.x * 256 + threadIdx.x;
    if (idx < 256 * 128) {
        int c = idx >> 8, k = idx & 255;
        Wt[c * 256 + k] = f2bf(W[k * 128 + c]);
    } else {
        int j = idx - 256 * 128;
        if (j < 128 * 128) {
            int c = j >> 7, k = j & 127;
            Vt[c * 128 + k] = f2bf(V[k * 128 + c]);
        }
    }
}

__device__ __forceinline__ bf16x8 pack8(float4 a, float4 b) {
    bf16x8 v;
    v[0] = (short)f2bf(a.x); v[1] = (short)f2bf(a.y);
    v[2] = (short)f2bf(a.z); v[3] = (short)f2bf(a.w);
    v[4] = (short)f2bf(b.x); v[5] = (short)f2bf(b.y);
    v[6] = (short)f2bf(b.z); v[7] = (short)f2bf(b.w);
    return v;
}

// GEMM1: hs16[r][c] = bf16( (sum_k xh[r][k] * W[k][c]) * dinv[r] ), K=256.
// Block: 256 thr = 4 waves, each wave 32 rows x 128 cols. No LDS.
__global__ __launch_bounds__(256) void gemm1_mfma_kernel(
    const float* __restrict__ x, const float* __restrict__ hidden,
    const unsigned short* __restrict__ Wt, const float* __restrict__ dinv,
    unsigned short* __restrict__ hs16, int N)
{
    const int lane = threadIdx.x & 63;
    const int wave = threadIdx.x >> 6;
    const int i16  = lane & 15;
    const int kg   = lane >> 4;          // 0..3
    const int koff = kg * 8;
    const int wrow0 = blockIdx.x * 128 + wave * 32;

    f32x4 acc[2][8];
#pragma unroll
    for (int m = 0; m < 2; ++m)
#pragma unroll
        for (int n = 0; n < 8; ++n) acc[m][n] = (f32x4){0.f, 0.f, 0.f, 0.f};

    int r[2], rl[2];
#pragma unroll
    for (int m = 0; m < 2; ++m) {
        r[m]  = wrow0 + m * 16 + i16;
        rl[m] = r[m] < N ? r[m] : N - 1;
    }

#pragma unroll
    for (int ks = 0; ks < 8; ++ks) {
        const int k0 = ks * 32;
        const float* __restrict__ src = (k0 < 128) ? x : hidden;
        const int kc = (k0 & 127) + koff;
        bf16x8 xf[2];
#pragma unroll
        for (int m = 0; m < 2; ++m) {
            const float* pa = src + (size_t)rl[m] * 128 + kc;
            float4 a = *(const float4*)pa;
            float4 b = *(const float4*)(pa + 4);
            xf[m] = pack8(a, b);
        }
#pragma unroll
        for (int n = 0; n < 8; ++n) {
            bf16x8 wf = *(const bf16x8*)(Wt + (size_t)(n * 16 + i16) * 256 + k0 + koff);
            acc[0][n] = __builtin_amdgcn_mfma_f32_16x16x32_bf16(wf, xf[0], acc[0][n], 0, 0, 0);
            acc[1][n] = __builtin_amdgcn_mfma_f32_16x16x32_bf16(wf, xf[1], acc[1][n], 0, 0, 0);
        }
    }

#pragma unroll
    for (int m = 0; m < 2; ++m) {
        if (r[m] < N) {
            const float s = dinv[r[m]];
            unsigned short* dst = hs16 + (size_t)r[m] * 128;
#pragma unroll
            for (int n = 0; n < 8; ++n) {
                const int c0 = n * 16 + kg * 4;
                s16x4 o;
                o[0] = (short)f2bf(acc[m][n][0] * s);
                o[1] = (short)f2bf(acc[m][n][1] * s);
                o[2] = (short)f2bf(acc[m][n][2] * s);
                o[3] = (short)f2bf(acc[m][n][3] * s);
                *(s16x4*)(dst + c0) = o;
            }
        }
    }
}

// --- prefix scan (3 kernels) ---
__global__ void scan_block_kernel(const unsigned int* degcnt, unsigned int* off,
                                  unsigned int* blocksum, int N) {
    __shared__ unsigned int s[256];
    int gid = blockIdx.x * 256 + threadIdx.x;
    unsigned int v = (gid < N) ? degcnt[gid] : 0u;
    s[threadIdx.x] = v;
    __syncthreads();
    for (int ofs = 1; ofs < 256; ofs <<= 1) {
        unsigned int tv = (threadIdx.x >= ofs) ? s[threadIdx.x - ofs] : 0u;
        __syncthreads();
        s[threadIdx.x] += tv;
        __syncthreads();
    }
    if (gid < N) off[gid] = s[threadIdx.x] - v;
    if (threadIdx.x == 255) blocksum[blockIdx.x] = s[255];
}

__global__ void scan_sums_kernel(unsigned int* blocksum, int nb) {
    __shared__ unsigned int s[1024];
    int tid = threadIdx.x;
    unsigned int v = (tid < nb) ? blocksum[tid] : 0u;
    s[tid] = v;
    __syncthreads();
    for (int ofs = 1; ofs < 1024; ofs <<= 1) {
        unsigned int tv = (tid >= ofs) ? s[tid - ofs] : 0u;
        __syncthreads();
        s[tid] += tv;
        __syncthreads();
    }
    if (tid < nb) blocksum[tid] = s[tid] - v;
}

__global__ void add_offsets_kernel(unsigned int* off, const unsigned int* blocksum, int N) {
    int gid = blockIdx.x * 256 + threadIdx.x;
    if (gid < N) off[gid] += blocksum[blockIdx.x];
}

__global__ void fill_csr_kernel(const int* __restrict__ edges32,
                                const unsigned int* __restrict__ off,
                                unsigned int* cursor, int* csr_src, long long E) {
    long long e = (long long)blockIdx.x * blockDim.x + threadIdx.x;
    if (e >= E) return;
    int s = edges32[e];
    int d = edges32[E + e];
    unsigned int pos = atomicAdd(&cursor[d], 1u);
    csr_src[off[d] + pos] = s;
}

// wave-per-node aggregation; lane owns cols {2*lane, 2*lane+1}
__global__ __launch_bounds__(256) void aggregate_kernel(
    const unsigned short* __restrict__ hs16, const int* __restrict__ csr_src,
    const unsigned int* __restrict__ off, const unsigned int* __restrict__ degcnt,
    const float* __restrict__ dinv, const float* __restrict__ bmat,
    const float* __restrict__ bias, float* __restrict__ out_nh,
    unsigned short* __restrict__ nh16, int N)
{
    const int lane = threadIdx.x & 63;
    const int n = blockIdx.x * 4 + (threadIdx.x >> 6);
    if (n >= N) return;
    const unsigned int start = off[n];
    const unsigned int cnt   = degcnt[n];
    const unsigned int* hsw = (const unsigned int*)hs16;   // 2 bf16 per word

    unsigned int v = hsw[(size_t)n * 64 + lane];           // self loop
    float ax = bflo(v), ay = bfhi(v);

    for (unsigned int base = 0; base < cnt; base += 64) {
        int idx = (base + lane < cnt) ? csr_src[start + base + lane] : 0;
        int m = (int)min(64u, cnt - base);
        for (int i = 0; i < m; ++i) {
            int s = __shfl(idx, i, 64);
            unsigned int u = hsw[(size_t)s * 64 + lane];
            ax += bflo(u);
            ay += bfhi(u);
        }
    }
    const float dn = dinv[n];
    const float2 bi = *(const float2*)(bias + lane * 2);
    const float2 bm = *(const float2*)(bmat + (size_t)n * 128 + lane * 2);
    float vx = bm.x + ax * dn + bi.x;
    float vy = bm.y + ay * dn + bi.y;
    float nx = 1.0f / (1.0f + __expf(-vx));
    float ny = 1.0f / (1.0f + __expf(-vy));
    *(float2*)(out_nh + (size_t)n * 128 + lane * 2) = make_float2(nx, ny);
    ((unsigned int*)nh16)[(size_t)n * 64 + lane] =
        (unsigned int)f2bf(nx) | ((unsigned int)f2bf(ny) << 16);
}

// GEMM2: o[r][c] = cmat[r][c] + sum_h nh[r][h] * V[h][c], K=128.
__global__ __launch_bounds__(256) void gemm2_mfma_kernel(
    const unsigned short* __restrict__ nh16, const unsigned short* __restrict__ Vt,
    const float* __restrict__ cmat, float* __restrict__ o, int N)
{
    const int lane = threadIdx.x & 63;
    const int wave = threadIdx.x >> 6;
    const int i16  = lane & 15;
    const int kg   = lane >> 4;
    const int koff = kg * 8;
    const int wrow0 = blockIdx.x * 128 + wave * 32;

    f32x4 acc[2][8];
#pragma unroll
    for (int m = 0; m < 2; ++m)
#pragma unroll
        for (int n = 0; n < 8; ++n) acc[m][n] = (f32x4){0.f, 0.f, 0.f, 0.f};

    int r[2], rl[2];
#pragma unroll
    for (int m = 0; m < 2; ++m) {
        r[m]  = wrow0 + m * 16 + i16;
        rl[m] = r[m] < N ? r[m] : N - 1;
    }

#pragma unroll
    for (int ks = 0; ks < 4; ++ks) {
        const int k0 = ks * 32;
        bf16x8 xf[2];
#pragma unroll
        for (int m = 0; m < 2; ++m)
            xf[m] = *(const bf16x8*)(nh16 + (size_t)rl[m] * 128 + k0 + koff);
#pragma unroll
        for (int n = 0; n < 8; ++n) {
            bf16x8 wf = *(const bf16x8*)(Vt + (size_t)(n * 16 + i16) * 128 + k0 + koff);
            acc[0][n] = __builtin_amdgcn_mfma_f32_16x16x32_bf16(wf, xf[0], acc[0][n], 0, 0, 0);
            acc[1][n] = __builtin_amdgcn_mfma_f32_16x16x32_bf16(wf, xf[1], acc[1][n], 0, 0, 0);
        }
    }

#pragma unroll
    for (int m = 0; m < 2; ++m) {
        if (r[m] < N) {
            const float* crow = cmat + (size_t)r[m] * 128;
            float* orow = o + (size_t)r[m] * 128;
#pragma unroll
            for (int n = 0; n < 8; ++n) {
                const int c0 = n * 16 + kg * 4;
                float4 c = *(const float4*)(crow + c0);
                float4 w = make_float4(acc[m][n][0] + c.x, acc[m][n][1] + c.y,
                                       acc[m][n][2] + c.z, acc[m][n][3] + c.w);
                *(float4*)(orow + c0) = w;
            }
        }
    }
}

extern "C" void kernel_launch(void* const* d_in, const int* in_sizes, int n_in,
                              void* d_out, int out_size, void* d_ws, size_t ws_size,
                              hipStream_t stream) {
    const float* x      = (const float*)d_in[0];
    const float* hidden = (const float*)d_in[1];
    const float* W      = (const float*)d_in[2];
    const float* bias   = (const float*)d_in[3];
    const float* bmat   = (const float*)d_in[4];
    const float* V      = (const float*)d_in[5];
    const float* cmat   = (const float*)d_in[6];
    const void*  eraw   = d_in[7];

    const int H = in_sizes[3];                 // 128
    const int F = in_sizes[5] / H;             // 128
    const int N = in_sizes[0] / F;             // 100000
    const long long twoE = in_sizes[7];
    const long long E    = twoE / 2;

    // ---- workspace layout ----
    char* p = (char*)d_ws;
    int* flag = (int*)p;                        p += 256;
    unsigned int* degcnt = (unsigned int*)p;    p += (size_t)N * 4;
    unsigned int* cursor = (unsigned int*)p;    p += (size_t)N * 4;   // contiguous w/ degcnt
    unsigned int* off    = (unsigned int*)p;    p += (size_t)N * 4;
    float* dinv          = (float*)p;           p += (size_t)N * 4;
    unsigned int* blocksum = (unsigned int*)p;  p += 4096;
    unsigned short* Wt   = (unsigned short*)p;  p += 256 * 128 * 2;
    unsigned short* Vt   = (unsigned short*)p;  p += 128 * 128 * 2;
    int* edges32         = (int*)p;             p += (size_t)twoE * 4;
    int* csr_src         = (int*)p;             p += (size_t)E * 4;
    unsigned short* hs16 = (unsigned short*)p;  p += (size_t)N * H * 2;
    unsigned short* nh16 = (unsigned short*)p;  p += (size_t)N * H * 2;

    float* out_o  = (float*)d_out;
    float* out_nh = (float*)d_out + (size_t)N * F;

    // 0. zero degcnt + cursor
    {
        long long nz = 2LL * N;
        zero_u32_kernel<<<(unsigned)((nz + 255) / 256), 256, 0, stream>>>(degcnt, nz);
    }
    // 1. dtype detect
    detect_dtype_kernel<<<1, 256, 0, stream>>>((const unsigned int*)eraw, flag);
    // 2. decode + degree histogram
    decode_edges_kernel<<<(unsigned)((twoE + 255) / 256), 256, 0, stream>>>(
        eraw, edges32, degcnt, twoE, E, N, flag);
    // 3. dinv
    dinv_kernel<<<(N + 255) / 256, 256, 0, stream>>>(degcnt, dinv, N);
    // 4. transposed bf16 weights
    prep_wt_kernel<<<192, 256, 0, stream>>>(W, V, Wt, Vt);
    // 5. GEMM1 (MFMA, scaled by dinv)
    gemm1_mfma_kernel<<<(N + 127) / 128, 256, 0, stream>>>(x, hidden, Wt, dinv, hs16, N);
    // 6. prefix scan -> off
    int nb = (N + 255) / 256;
    scan_block_kernel<<<nb, 256, 0, stream>>>(degcnt, off, blocksum, N);
    scan_sums_kernel<<<1, 1024, 0, stream>>>(blocksum, nb);
    add_offsets_kernel<<<nb, 256, 0, stream>>>(off, blocksum, N);
    // 7. fill CSR
    fill_csr_kernel<<<(unsigned)((E + 255) / 256), 256, 0, stream>>>(
        edges32, off, cursor, csr_src, E);
    // 8. aggregate + sigmoid -> new_hidden (f32) + nh16 (bf16)
    aggregate_kernel<<<(N + 3) / 4, 256, 0, stream>>>(hs16, csr_src, off, degcnt, dinv,
                                                      bmat, bias, out_nh, nh16, N);
    // 9. GEMM2 -> o
    gemm2_mfma_kernel<<<(N + 127) / 128, 256, 0, stream>>>(nh16, Vt, cmat, out_o, N);
}

// Round 3
// 380.687 us; speedup vs baseline: 1.8769x; 1.1515x over previous
//
#include <hip/hip_runtime.h>

// ---------------------------------------------------------------------------
// ConvRNN GCN cell — bf16-MFMA GEMMs + CSR gather aggregation.
//   0. zero degcnt/cursor
//   1. detect edge dtype (int64 vs int32)
//   2. decode edges -> int32, in-degree histogram
//   3. dinv = rsqrt(deg+1)
//   4. Wt/Vt = bf16 transposed weights (for MFMA A-operand fragments)
//   5. GEMM1 (MFMA): hs16 = bf16(([x|hidden] @ W) * dinv[row])
//   6. prefix scan -> CSR offsets; fill CSR
//   7. aggregate (wave/node, 8-deep pipelined gather):
//      nh = sigmoid(b + (sum hs16[src] + hs16[n])*dinv + bias)
//   8. GEMM2 (MFMA): o = cmat + nh16 @ V
// ---------------------------------------------------------------------------

typedef __attribute__((ext_vector_type(8))) short bf16x8;
typedef __attribute__((ext_vector_type(4))) short s16x4;
typedef __attribute__((ext_vector_type(4))) float f32x4;

__device__ __forceinline__ unsigned short f2bf(float f) {
    unsigned int u = __float_as_uint(f);
    unsigned int r = u + 0x7fffu + ((u >> 16) & 1u);   // round-to-nearest-even
    return (unsigned short)(r >> 16);
}
__device__ __forceinline__ float bflo(unsigned int u) { return __uint_as_float(u << 16); }
__device__ __forceinline__ float bfhi(unsigned int u) { return __uint_as_float(u & 0xffff0000u); }

__global__ void zero_u32_kernel(unsigned int* p, long long n) {
    long long i = (long long)blockIdx.x * blockDim.x + threadIdx.x;
    if (i < n) p[i] = 0u;
}

__global__ void detect_dtype_kernel(const unsigned int* e, int* flag) {
    __shared__ int nz;
    if (threadIdx.x == 0) nz = 0;
    __syncthreads();
    for (int i = threadIdx.x; i < 512; i += blockDim.x)
        if (e[2 * i + 1] != 0u) nz = 1;
    __syncthreads();
    if (threadIdx.x == 0) *flag = (nz == 0) ? 1 : 0;
}

__global__ void decode_edges_kernel(const void* eraw, int* edges32,
                                    unsigned int* degcnt,
                                    long long twoE, long long E, int N,
                                    const int* flag) {
    long long i = (long long)blockIdx.x * blockDim.x + threadIdx.x;
    if (i >= twoE) return;
    int v;
    if (*flag) v = (int)((const long long*)eraw)[i];
    else       v = ((const int*)eraw)[i];
    v = v < 0 ? 0 : (v >= N ? N - 1 : v);
    edges32[i] = v;
    if (i >= E) atomicAdd(&degcnt[v], 1u);   // dst half
}

__global__ void dinv_kernel(const unsigned int* degcnt, float* dinv, int N) {
    int n = blockIdx.x * blockDim.x + threadIdx.x;
    if (n < N) dinv[n] = rsqrtf((float)(degcnt[n] + 1u));
}

// Wt[c][k] = bf16(W[k][c])  (128 x 256);  Vt[c][k] = bf16(V[k][c])  (128 x 128)
__global__ void prep_wt_kernel(const float* __restrict__ W, const float* __restrict__ V,
                               unsigned short* __restrict__ Wt, unsigned short* __restrict__ Vt) {
    int idx = blockIdx.x * 256 + threadIdx.x;
    if (idx < 256 * 128) {
        int c = idx >> 8, k = idx & 255;
        Wt[c * 256 + k] = f2bf(W[k * 128 + c]);
    } else {
        int j = idx - 256 * 128;
        if (j < 128 * 128) {
            int c = j >> 7, k = j & 127;
            Vt[c * 128 + k] = f2bf(V[k * 128 + c]);
        }
    }
}

__device__ __forceinline__ bf16x8 pack8(float4 a, float4 b) {
    bf16x8 v;
    v[0] = (short)f2bf(a.x); v[1] = (short)f2bf(a.y);
    v[2] = (short)f2bf(a.z); v[3] = (short)f2bf(a.w);
    v[4] = (short)f2bf(b.x); v[5] = (short)f2bf(b.y);
    v[6] = (short)f2bf(b.z); v[7] = (short)f2bf(b.w);
    return v;
}

// GEMM1: hs16[r][c] = bf16( (sum_k xh[r][k] * W[k][c]) * dinv[r] ), K=256.
__global__ __launch_bounds__(256) void gemm1_mfma_kernel(
    const float* __restrict__ x, const float* __restrict__ hidden,
    const unsigned short* __restrict__ Wt, const float* __restrict__ dinv,
    unsigned short* __restrict__ hs16, int N)
{
    const int lane = threadIdx.x & 63;
    const int wave = threadIdx.x >> 6;
    const int i16  = lane & 15;
    const int kg   = lane >> 4;          // 0..3
    const int koff = kg * 8;
    const int wrow0 = blockIdx.x * 128 + wave * 32;

    f32x4 acc[2][8];
#pragma unroll
    for (int m = 0; m < 2; ++m)
#pragma unroll
        for (int n = 0; n < 8; ++n) acc[m][n] = (f32x4){0.f, 0.f, 0.f, 0.f};

    int r[2], rl[2];
#pragma unroll
    for (int m = 0; m < 2; ++m) {
        r[m]  = wrow0 + m * 16 + i16;
        rl[m] = r[m] < N ? r[m] : N - 1;
    }

#pragma unroll
    for (int ks = 0; ks < 8; ++ks) {
        const int k0 = ks * 32;
        const float* __restrict__ src = (k0 < 128) ? x : hidden;
        const int kc = (k0 & 127) + koff;
        bf16x8 xf[2];
#pragma unroll
        for (int m = 0; m < 2; ++m) {
            const float* pa = src + (size_t)rl[m] * 128 + kc;
            float4 a = *(const float4*)pa;
            float4 b = *(const float4*)(pa + 4);
            xf[m] = pack8(a, b);
        }
#pragma unroll
        for (int n = 0; n < 8; ++n) {
            bf16x8 wf = *(const bf16x8*)(Wt + (size_t)(n * 16 + i16) * 256 + k0 + koff);
            acc[0][n] = __builtin_amdgcn_mfma_f32_16x16x32_bf16(wf, xf[0], acc[0][n], 0, 0, 0);
            acc[1][n] = __builtin_amdgcn_mfma_f32_16x16x32_bf16(wf, xf[1], acc[1][n], 0, 0, 0);
        }
    }

#pragma unroll
    for (int m = 0; m < 2; ++m) {
        if (r[m] < N) {
            const float s = dinv[r[m]];
            unsigned short* dst = hs16 + (size_t)r[m] * 128;
#pragma unroll
            for (int n = 0; n < 8; ++n) {
                const int c0 = n * 16 + kg * 4;
                s16x4 o;
                o[0] = (short)f2bf(acc[m][n][0] * s);
                o[1] = (short)f2bf(acc[m][n][1] * s);
                o[2] = (short)f2bf(acc[m][n][2] * s);
                o[3] = (short)f2bf(acc[m][n][3] * s);
                *(s16x4*)(dst + c0) = o;
            }
        }
    }
}

// --- prefix scan (3 kernels) ---
__global__ void scan_block_kernel(const unsigned int* degcnt, unsigned int* off,
                                  unsigned int* blocksum, int N) {
    __shared__ unsigned int s[256];
    int gid = blockIdx.x * 256 + threadIdx.x;
    unsigned int v = (gid < N) ? degcnt[gid] : 0u;
    s[threadIdx.x] = v;
    __syncthreads();
    for (int ofs = 1; ofs < 256; ofs <<= 1) {
        unsigned int tv = (threadIdx.x >= ofs) ? s[threadIdx.x - ofs] : 0u;
        __syncthreads();
        s[threadIdx.x] += tv;
        __syncthreads();
    }
    if (gid < N) off[gid] = s[threadIdx.x] - v;
    if (threadIdx.x == 255) blocksum[blockIdx.x] = s[255];
}

__global__ void scan_sums_kernel(unsigned int* blocksum, int nb) {
    __shared__ unsigned int s[1024];
    int tid = threadIdx.x;
    unsigned int v = (tid < nb) ? blocksum[tid] : 0u;
    s[tid] = v;
    __syncthreads();
    for (int ofs = 1; ofs < 1024; ofs <<= 1) {
        unsigned int tv = (tid >= ofs) ? s[tid - ofs] : 0u;
        __syncthreads();
        s[tid] += tv;
        __syncthreads();
    }
    if (tid < nb) blocksum[tid] = s[tid] - v;
}

__global__ void add_offsets_kernel(unsigned int* off, const unsigned int* blocksum, int N) {
    int gid = blockIdx.x * 256 + threadIdx.x;
    if (gid < N) off[gid] += blocksum[blockIdx.x];
}

__global__ void fill_csr_kernel(const int* __restrict__ edges32,
                                const unsigned int* __restrict__ off,
                                unsigned int* cursor, int* csr_src, long long E) {
    long long e = (long long)blockIdx.x * blockDim.x + threadIdx.x;
    if (e >= E) return;
    int s = edges32[e];
    int d = edges32[E + e];
    unsigned int pos = atomicAdd(&cursor[d], 1u);
    csr_src[off[d] + pos] = s;
}

// wave-per-node aggregation; lane owns cols {2*lane, 2*lane+1}.
// 8-deep software-pipelined gather: 8 independent loads in flight per wave.
__global__ __launch_bounds__(256) void aggregate_kernel(
    const unsigned short* __restrict__ hs16, const int* __restrict__ csr_src,
    const unsigned int* __restrict__ off, const unsigned int* __restrict__ degcnt,
    const float* __restrict__ dinv, const float* __restrict__ bmat,
    const float* __restrict__ bias, float* __restrict__ out_nh,
    unsigned short* __restrict__ nh16, int N)
{
    const int lane = threadIdx.x & 63;
    const int n = blockIdx.x * 4 + (threadIdx.x >> 6);
    if (n >= N) return;
    const unsigned int start = off[n];
    const unsigned int cnt   = degcnt[n];
    const unsigned int* hsw = (const unsigned int*)hs16;   // 2 bf16 per word

    unsigned int v = hsw[(size_t)n * 64 + lane];           // self loop
    float ax = bflo(v), ay = bfhi(v);

    for (unsigned int base = 0; base < cnt; base += 64) {
        int idx = (base + lane < cnt) ? csr_src[start + base + lane] : 0;
        int m = (int)min(64u, cnt - base);
        int i = 0;
        // 8-wide: issue 8 independent gathers before consuming
        for (; i + 8 <= m; i += 8) {
            int s0 = __shfl(idx, i,     64), s1 = __shfl(idx, i + 1, 64);
            int s2 = __shfl(idx, i + 2, 64), s3 = __shfl(idx, i + 3, 64);
            int s4 = __shfl(idx, i + 4, 64), s5 = __shfl(idx, i + 5, 64);
            int s6 = __shfl(idx, i + 6, 64), s7 = __shfl(idx, i + 7, 64);
            unsigned int u0 = hsw[(size_t)s0 * 64 + lane];
            unsigned int u1 = hsw[(size_t)s1 * 64 + lane];
            unsigned int u2 = hsw[(size_t)s2 * 64 + lane];
            unsigned int u3 = hsw[(size_t)s3 * 64 + lane];
            unsigned int u4 = hsw[(size_t)s4 * 64 + lane];
            unsigned int u5 = hsw[(size_t)s5 * 64 + lane];
            unsigned int u6 = hsw[(size_t)s6 * 64 + lane];
            unsigned int u7 = hsw[(size_t)s7 * 64 + lane];
            ax += bflo(u0); ay += bfhi(u0);
            ax += bflo(u1); ay += bfhi(u1);
            ax += bflo(u2); ay += bfhi(u2);
            ax += bflo(u3); ay += bfhi(u3);
            ax += bflo(u4); ay += bfhi(u4);
            ax += bflo(u5); ay += bfhi(u5);
            ax += bflo(u6); ay += bfhi(u6);
            ax += bflo(u7); ay += bfhi(u7);
        }
        for (; i + 2 <= m; i += 2) {
            int s0 = __shfl(idx, i, 64), s1 = __shfl(idx, i + 1, 64);
            unsigned int u0 = hsw[(size_t)s0 * 64 + lane];
            unsigned int u1 = hsw[(size_t)s1 * 64 + lane];
            ax += bflo(u0); ay += bfhi(u0);
            ax += bflo(u1); ay += bfhi(u1);
        }
        for (; i < m; ++i) {
            int s = __shfl(idx, i, 64);
            unsigned int u = hsw[(size_t)s * 64 + lane];
            ax += bflo(u); ay += bfhi(u);
        }
    }
    const float dn = dinv[n];
    const float2 bi = *(const float2*)(bias + lane * 2);
    const float2 bm = *(const float2*)(bmat + (size_t)n * 128 + lane * 2);
    float vx = bm.x + ax * dn + bi.x;
    float vy = bm.y + ay * dn + bi.y;
    float nx = 1.0f / (1.0f + __expf(-vx));
    float ny = 1.0f / (1.0f + __expf(-vy));
    *(float2*)(out_nh + (size_t)n * 128 + lane * 2) = make_float2(nx, ny);
    ((unsigned int*)nh16)[(size_t)n * 64 + lane] =
        (unsigned int)f2bf(nx) | ((unsigned int)f2bf(ny) << 16);
}

// GEMM2: o[r][c] = cmat[r][c] + sum_h nh[r][h] * V[h][c], K=128.
__global__ __launch_bounds__(256) void gemm2_mfma_kernel(
    const unsigned short* __restrict__ nh16, const unsigned short* __restrict__ Vt,
    const float* __restrict__ cmat, float* __restrict__ o, int N)
{
    const int lane = threadIdx.x & 63;
    const int wave = threadIdx.x >> 6;
    const int i16  = lane & 15;
    const int kg   = lane >> 4;
    const int koff = kg * 8;
    const int wrow0 = blockIdx.x * 128 + wave * 32;

    f32x4 acc[2][8];
#pragma unroll
    for (int m = 0; m < 2; ++m)
#pragma unroll
        for (int n = 0; n < 8; ++n) acc[m][n] = (f32x4){0.f, 0.f, 0.f, 0.f};

    int r[2], rl[2];
#pragma unroll
    for (int m = 0; m < 2; ++m) {
        r[m]  = wrow0 + m * 16 + i16;
        rl[m] = r[m] < N ? r[m] : N - 1;
    }

#pragma unroll
    for (int ks = 0; ks < 4; ++ks) {
        const int k0 = ks * 32;
        bf16x8 xf[2];
#pragma unroll
        for (int m = 0; m < 2; ++m)
            xf[m] = *(const bf16x8*)(nh16 + (size_t)rl[m] * 128 + k0 + koff);
#pragma unroll
        for (int n = 0; n < 8; ++n) {
            bf16x8 wf = *(const bf16x8*)(Vt + (size_t)(n * 16 + i16) * 128 + k0 + koff);
            acc[0][n] = __builtin_amdgcn_mfma_f32_16x16x32_bf16(wf, xf[0], acc[0][n], 0, 0, 0);
            acc[1][n] = __builtin_amdgcn_mfma_f32_16x16x32_bf16(wf, xf[1], acc[1][n], 0, 0, 0);
        }
    }

#pragma unroll
    for (int m = 0; m < 2; ++m) {
        if (r[m] < N) {
            const float* crow = cmat + (size_t)r[m] * 128;
            float* orow = o + (size_t)r[m] * 128;
#pragma unroll
            for (int n = 0; n < 8; ++n) {
                const int c0 = n * 16 + kg * 4;
                float4 c = *(const float4*)(crow + c0);
                float4 w = make_float4(acc[m][n][0] + c.x, acc[m][n][1] + c.y,
                                       acc[m][n][2] + c.z, acc[m][n][3] + c.w);
                *(float4*)(orow + c0) = w;
            }
        }
    }
}

extern "C" void kernel_launch(void* const* d_in, const int* in_sizes, int n_in,
                              void* d_out, int out_size, void* d_ws, size_t ws_size,
                              hipStream_t stream) {
    const float* x      = (const float*)d_in[0];
    const float* hidden = (const float*)d_in[1];
    const float* W      = (const float*)d_in[2];
    const float* bias   = (const float*)d_in[3];
    const float* bmat   = (const float*)d_in[4];
    const float* V      = (const float*)d_in[5];
    const float* cmat   = (const float*)d_in[6];
    const void*  eraw   = d_in[7];

    const int H = in_sizes[3];                 // 128
    const int F = in_sizes[5] / H;             // 128
    const int N = in_sizes[0] / F;             // 100000
    const long long twoE = in_sizes[7];
    const long long E    = twoE / 2;

    // ---- workspace layout ----
    char* p = (char*)d_ws;
    int* flag = (int*)p;                        p += 256;
    unsigned int* degcnt = (unsigned int*)p;    p += (size_t)N * 4;
    unsigned int* cursor = (unsigned int*)p;    p += (size_t)N * 4;   // contiguous w/ degcnt
    unsigned int* off    = (unsigned int*)p;    p += (size_t)N * 4;
    float* dinv          = (float*)p;           p += (size_t)N * 4;
    unsigned int* blocksum = (unsigned int*)p;  p += 4096;
    unsigned short* Wt   = (unsigned short*)p;  p += 256 * 128 * 2;
    unsigned short* Vt   = (unsigned short*)p;  p += 128 * 128 * 2;
    int* edges32         = (int*)p;             p += (size_t)twoE * 4;
    int* csr_src         = (int*)p;             p += (size_t)E * 4;
    unsigned short* hs16 = (unsigned short*)p;  p += (size_t)N * H * 2;
    unsigned short* nh16 = (unsigned short*)p;  p += (size_t)N * H * 2;

    float* out_o  = (float*)d_out;
    float* out_nh = (float*)d_out + (size_t)N * F;

    // 0. zero degcnt + cursor
    {
        long long nz = 2LL * N;
        zero_u32_kernel<<<(unsigned)((nz + 255) / 256), 256, 0, stream>>>(degcnt, nz);
    }
    // 1. dtype detect
    detect_dtype_kernel<<<1, 256, 0, stream>>>((const unsigned int*)eraw, flag);
    // 2. decode + degree histogram
    decode_edges_kernel<<<(unsigned)((twoE + 255) / 256), 256, 0, stream>>>(
        eraw, edges32, degcnt, twoE, E, N, flag);
    // 3. dinv
    dinv_kernel<<<(N + 255) / 256, 256, 0, stream>>>(degcnt, dinv, N);
    // 4. transposed bf16 weights
    prep_wt_kernel<<<192, 256, 0, stream>>>(W, V, Wt, Vt);
    // 5. GEMM1 (MFMA, scaled by dinv)
    gemm1_mfma_kernel<<<(N + 127) / 128, 256, 0, stream>>>(x, hidden, Wt, dinv, hs16, N);
    // 6. prefix scan -> off
    int nb = (N + 255) / 256;
    scan_block_kernel<<<nb, 256, 0, stream>>>(degcnt, off, blocksum, N);
    scan_sums_kernel<<<1, 1024, 0, stream>>>(blocksum, nb);
    add_offsets_kernel<<<nb, 256, 0, stream>>>(off, blocksum, N);
    // 7. fill CSR
    fill_csr_kernel<<<(unsigned)((E + 255) / 256), 256, 0, stream>>>(
        edges32, off, cursor, csr_src, E);
    // 8. aggregate + sigmoid -> new_hidden (f32) + nh16 (bf16)
    aggregate_kernel<<<(N + 3) / 4, 256, 0, stream>>>(hs16, csr_src, off, degcnt, dinv,
                                                      bmat, bias, out_nh, nh16, N);
    // 9. GEMM2 -> o
    gemm2_mfma_kernel<<<(N + 127) / 128, 256, 0, stream>>>(nh16, Vt, cmat, out_o, N);
}

// Round 4
// 270.782 us; speedup vs baseline: 2.6387x; 1.4059x over previous
//
#include <hip/hip_runtime.h>

// ---------------------------------------------------------------------------
// ConvRNN GCN cell — bf16-MFMA GEMMs + bucketed counting-sort CSR + gather.
//   1. detect edge dtype (int64 vs int32)
//   2. bucket_count: per-block LDS hist of dst>>9 -> bucket_cnt (196 buckets)
//   3. bucket_scan:  exclusive scan of bucket_cnt -> bucket_base (CSR coords)
//   4. partition:    scatter packed (src,dst) records into bucket regions
//   5. bucket_fill:  per-bucket LDS degree hist + scan -> off/degcnt/dinv
//                    (coalesced) + exact CSR scatter via LDS atomics
//   6. GEMM1 (MFMA): hs16 = bf16(([x|hidden] @ W) * dinv[row])
//   7. aggregate (wave/node, 8-deep pipelined gather) -> new_hidden + nh16
//   8. GEMM2 (MFMA): o = cmat + nh16 @ V
// No random global atomics anywhere.
// ---------------------------------------------------------------------------

typedef __attribute__((ext_vector_type(8))) short bf16x8;
typedef __attribute__((ext_vector_type(4))) short s16x4;
typedef __attribute__((ext_vector_type(4))) float f32x4;

__device__ __forceinline__ unsigned short f2bf(float f) {
    unsigned int u = __float_as_uint(f);
    unsigned int r = u + 0x7fffu + ((u >> 16) & 1u);   // round-to-nearest-even
    return (unsigned short)(r >> 16);
}
__device__ __forceinline__ float bflo(unsigned int u) { return __uint_as_float(u << 16); }
__device__ __forceinline__ float bfhi(unsigned int u) { return __uint_as_float(u & 0xffff0000u); }

__global__ void zero_small_kernel(unsigned int* p, int n) {
    int i = blockIdx.x * 256 + threadIdx.x;
    if (i < n) p[i] = 0u;
}

__global__ void detect_dtype_kernel(const unsigned int* e, int* flag) {
    __shared__ int nz;
    if (threadIdx.x == 0) nz = 0;
    __syncthreads();
    for (int i = threadIdx.x; i < 512; i += blockDim.x)
        if (e[2 * i + 1] != 0u) nz = 1;
    __syncthreads();
    if (threadIdx.x == 0) *flag = (nz == 0) ? 1 : 0;
}

// per-block LDS histogram of dst buckets -> global bucket_cnt
__global__ __launch_bounds__(256) void bucket_count_kernel(
    const void* __restrict__ eraw, const int* __restrict__ flag,
    unsigned int* __restrict__ bucket_cnt, long long E, int N)
{
    __shared__ unsigned int hist[256];
    const int t = threadIdx.x;
    hist[t] = 0u;
    __syncthreads();
    const int is64 = *flag;
    long long i0 = (long long)blockIdx.x * 8192;
    long long iend = i0 + 8192; if (iend > E) iend = E;
    if (is64) {
        const long long* dp = (const long long*)eraw + E;
        for (long long i = i0 + t; i < iend; i += 256) {
            int d = (int)dp[i];
            d = d < 0 ? 0 : (d >= N ? N - 1 : d);
            atomicAdd(&hist[d >> 9], 1u);
        }
    } else {
        const int* dp = (const int*)eraw + E;
        for (long long i = i0 + t; i < iend; i += 256) {
            int d = dp[i];
            d = d < 0 ? 0 : (d >= N ? N - 1 : d);
            atomicAdd(&hist[d >> 9], 1u);
        }
    }
    __syncthreads();
    unsigned int h = hist[t];
    if (h) atomicAdd(&bucket_cnt[t], h);
}

// exclusive scan of <=256 bucket counts; base[nbkt] = E
__global__ void bucket_scan_kernel(const unsigned int* __restrict__ cnt,
                                   unsigned int* __restrict__ base,
                                   int nbkt, unsigned int Etot) {
    __shared__ unsigned int s[256];
    int t = threadIdx.x;
    unsigned int v = (t < nbkt) ? cnt[t] : 0u;
    s[t] = v;
    __syncthreads();
    for (int o = 1; o < 256; o <<= 1) {
        unsigned int x = (t >= o) ? s[t - o] : 0u;
        __syncthreads();
        s[t] += x;
        __syncthreads();
    }
    if (t < nbkt) base[t] = s[t] - v;
    if (t == 0) base[nbkt] = Etot;
}

// scatter packed (src,dst) records into bucket regions (CSR coordinates);
// per-block LDS hist + single global bump per touched bucket.
__global__ __launch_bounds__(256) void partition_kernel(
    const void* __restrict__ eraw, const int* __restrict__ flag,
    const unsigned int* __restrict__ bucket_base,
    unsigned int* __restrict__ bucket_cursor,
    uint2* __restrict__ recs, long long E, int N)
{
    __shared__ unsigned int hist[256];
    __shared__ unsigned int base[256];
    const int t = threadIdx.x;
    hist[t] = 0u;
    __syncthreads();
    const int is64 = *flag;
    long long i0 = (long long)blockIdx.x * 4096;
    long long iend = i0 + 4096; if (iend > E) iend = E;

    if (is64) {
        const long long* dp = (const long long*)eraw + E;
        for (long long i = i0 + t; i < iend; i += 256) {
            int d = (int)dp[i]; d = d < 0 ? 0 : (d >= N ? N - 1 : d);
            atomicAdd(&hist[d >> 9], 1u);
        }
    } else {
        const int* dp = (const int*)eraw + E;
        for (long long i = i0 + t; i < iend; i += 256) {
            int d = dp[i]; d = d < 0 ? 0 : (d >= N ? N - 1 : d);
            atomicAdd(&hist[d >> 9], 1u);
        }
    }
    __syncthreads();
    unsigned int h = hist[t];
    if (h) base[t] = bucket_base[t] + atomicAdd(&bucket_cursor[t], h);
    __syncthreads();
    hist[t] = 0u;
    __syncthreads();

    if (is64) {
        const long long* sp = (const long long*)eraw;
        const long long* dp = sp + E;
        for (long long i = i0 + t; i < iend; i += 256) {
            int s = (int)sp[i]; s = s < 0 ? 0 : (s >= N ? N - 1 : s);
            int d = (int)dp[i]; d = d < 0 ? 0 : (d >= N ? N - 1 : d);
            int bk = d >> 9;
            unsigned int pos = base[bk] + atomicAdd(&hist[bk], 1u);
            recs[pos] = make_uint2((unsigned)s, (unsigned)d);
        }
    } else {
        const int* sp = (const int*)eraw;
        const int* dp = sp + E;
        for (long long i = i0 + t; i < iend; i += 256) {
            int s = sp[i]; s = s < 0 ? 0 : (s >= N ? N - 1 : s);
            int d = dp[i]; d = d < 0 ? 0 : (d >= N ? N - 1 : d);
            int bk = d >> 9;
            unsigned int pos = base[bk] + atomicAdd(&hist[bk], 1u);
            recs[pos] = make_uint2((unsigned)s, (unsigned)d);
        }
    }
}

// per-bucket: LDS degree hist over 512 local dsts, LDS scan -> off/degcnt/dinv
// (coalesced global writes), then exact CSR scatter via LDS cursor atomics.
__global__ __launch_bounds__(256) void bucket_fill_kernel(
    const uint2* __restrict__ recs, const unsigned int* __restrict__ bucket_base,
    unsigned int* __restrict__ off, unsigned int* __restrict__ degcnt,
    float* __restrict__ dinv, int* __restrict__ csr_src, int N)
{
    __shared__ unsigned int ldeg[512];
    __shared__ unsigned int lscan[256];
    const int t = threadIdx.x;
    const int b = blockIdx.x;
    const int d0 = b << 9;
    const unsigned int rstart = bucket_base[b];
    const unsigned int rend   = bucket_base[b + 1];
    ldeg[t] = 0u; ldeg[t + 256] = 0u;
    __syncthreads();
    for (unsigned int i = rstart + t; i < rend; i += 256)
        atomicAdd(&ldeg[recs[i].y - (unsigned)d0], 1u);
    __syncthreads();
    unsigned int a0 = ldeg[2 * t], a1 = ldeg[2 * t + 1];
    unsigned int ps = a0 + a1;
    lscan[t] = ps;
    __syncthreads();
    for (int o = 1; o < 256; o <<= 1) {
        unsigned int x = (t >= o) ? lscan[t - o] : 0u;
        __syncthreads();
        lscan[t] += x;
        __syncthreads();
    }
    unsigned int ex = lscan[t] - ps;
    unsigned int o0 = rstart + ex;
    unsigned int o1 = o0 + a0;
    int dA = d0 + 2 * t, dB = dA + 1;
    if (dA < N) { off[dA] = o0; degcnt[dA] = a0; dinv[dA] = rsqrtf((float)(a0 + 1u)); }
    if (dB < N) { off[dB] = o1; degcnt[dB] = a1; dinv[dB] = rsqrtf((float)(a1 + 1u)); }
    ldeg[2 * t]     = o0;     // reuse as absolute cursors
    ldeg[2 * t + 1] = o1;
    __syncthreads();
    for (unsigned int i = rstart + t; i < rend; i += 256) {
        uint2 r = recs[i];
        unsigned int slot = atomicAdd(&ldeg[r.y - (unsigned)d0], 1u);
        csr_src[slot] = (int)r.x;
    }
}

// Wt[c][k] = bf16(W[k][c])  (128 x 256);  Vt[c][k] = bf16(V[k][c])  (128 x 128)
__global__ void prep_wt_kernel(const float* __restrict__ W, const float* __restrict__ V,
                               unsigned short* __restrict__ Wt, unsigned short* __restrict__ Vt) {
    int idx = blockIdx.x * 256 + threadIdx.x;
    if (idx < 256 * 128) {
        int c = idx >> 8, k = idx & 255;
        Wt[c * 256 + k] = f2bf(W[k * 128 + c]);
    } else {
        int j = idx - 256 * 128;
        if (j < 128 * 128) {
            int c = j >> 7, k = j & 127;
            Vt[c * 128 + k] = f2bf(V[k * 128 + c]);
        }
    }
}

__device__ __forceinline__ bf16x8 pack8(float4 a, float4 b) {
    bf16x8 v;
    v[0] = (short)f2bf(a.x); v[1] = (short)f2bf(a.y);
    v[2] = (short)f2bf(a.z); v[3] = (short)f2bf(a.w);
    v[4] = (short)f2bf(b.x); v[5] = (short)f2bf(b.y);
    v[6] = (short)f2bf(b.z); v[7] = (short)f2bf(b.w);
    return v;
}

// GEMM1: hs16[r][c] = bf16( (sum_k xh[r][k] * W[k][c]) * dinv[r] ), K=256.
__global__ __launch_bounds__(256) void gemm1_mfma_kernel(
    const float* __restrict__ x, const float* __restrict__ hidden,
    const unsigned short* __restrict__ Wt, const float* __restrict__ dinv,
    unsigned short* __restrict__ hs16, int N)
{
    const int lane = threadIdx.x & 63;
    const int wave = threadIdx.x >> 6;
    const int i16  = lane & 15;
    const int kg   = lane >> 4;          // 0..3
    const int koff = kg * 8;
    const int wrow0 = blockIdx.x * 128 + wave * 32;

    f32x4 acc[2][8];
#pragma unroll
    for (int m = 0; m < 2; ++m)
#pragma unroll
        for (int n = 0; n < 8; ++n) acc[m][n] = (f32x4){0.f, 0.f, 0.f, 0.f};

    int r[2], rl[2];
#pragma unroll
    for (int m = 0; m < 2; ++m) {
        r[m]  = wrow0 + m * 16 + i16;
        rl[m] = r[m] < N ? r[m] : N - 1;
    }

#pragma unroll
    for (int ks = 0; ks < 8; ++ks) {
        const int k0 = ks * 32;
        const float* __restrict__ src = (k0 < 128) ? x : hidden;
        const int kc = (k0 & 127) + koff;
        bf16x8 xf[2];
#pragma unroll
        for (int m = 0; m < 2; ++m) {
            const float* pa = src + (size_t)rl[m] * 128 + kc;
            float4 a = *(const float4*)pa;
            float4 b = *(const float4*)(pa + 4);
            xf[m] = pack8(a, b);
        }
#pragma unroll
        for (int n = 0; n < 8; ++n) {
            bf16x8 wf = *(const bf16x8*)(Wt + (size_t)(n * 16 + i16) * 256 + k0 + koff);
            acc[0][n] = __builtin_amdgcn_mfma_f32_16x16x32_bf16(wf, xf[0], acc[0][n], 0, 0, 0);
            acc[1][n] = __builtin_amdgcn_mfma_f32_16x16x32_bf16(wf, xf[1], acc[1][n], 0, 0, 0);
        }
    }

#pragma unroll
    for (int m = 0; m < 2; ++m) {
        if (r[m] < N) {
            const float s = dinv[r[m]];
            unsigned short* dst = hs16 + (size_t)r[m] * 128;
#pragma unroll
            for (int n = 0; n < 8; ++n) {
                const int c0 = n * 16 + kg * 4;
                s16x4 o;
                o[0] = (short)f2bf(acc[m][n][0] * s);
                o[1] = (short)f2bf(acc[m][n][1] * s);
                o[2] = (short)f2bf(acc[m][n][2] * s);
                o[3] = (short)f2bf(acc[m][n][3] * s);
                *(s16x4*)(dst + c0) = o;
            }
        }
    }
}

// wave-per-node aggregation; lane owns cols {2*lane, 2*lane+1}.
// 8-deep software-pipelined gather: 8 independent loads in flight per wave.
__global__ __launch_bounds__(256) void aggregate_kernel(
    const unsigned short* __restrict__ hs16, const int* __restrict__ csr_src,
    const unsigned int* __restrict__ off, const unsigned int* __restrict__ degcnt,
    const float* __restrict__ dinv, const float* __restrict__ bmat,
    const float* __restrict__ bias, float* __restrict__ out_nh,
    unsigned short* __restrict__ nh16, int N)
{
    const int lane = threadIdx.x & 63;
    const int n = blockIdx.x * 4 + (threadIdx.x >> 6);
    if (n >= N) return;
    const unsigned int start = off[n];
    const unsigned int cnt   = degcnt[n];
    const unsigned int* hsw = (const unsigned int*)hs16;   // 2 bf16 per word

    unsigned int v = hsw[(size_t)n * 64 + lane];           // self loop
    float ax = bflo(v), ay = bfhi(v);

    for (unsigned int base = 0; base < cnt; base += 64) {
        int idx = (base + lane < cnt) ? csr_src[start + base + lane] : 0;
        int m = (int)min(64u, cnt - base);
        int i = 0;
        for (; i + 8 <= m; i += 8) {
            int s0 = __shfl(idx, i,     64), s1 = __shfl(idx, i + 1, 64);
            int s2 = __shfl(idx, i + 2, 64), s3 = __shfl(idx, i + 3, 64);
            int s4 = __shfl(idx, i + 4, 64), s5 = __shfl(idx, i + 5, 64);
            int s6 = __shfl(idx, i + 6, 64), s7 = __shfl(idx, i + 7, 64);
            unsigned int u0 = hsw[(size_t)s0 * 64 + lane];
            unsigned int u1 = hsw[(size_t)s1 * 64 + lane];
            unsigned int u2 = hsw[(size_t)s2 * 64 + lane];
            unsigned int u3 = hsw[(size_t)s3 * 64 + lane];
            unsigned int u4 = hsw[(size_t)s4 * 64 + lane];
            unsigned int u5 = hsw[(size_t)s5 * 64 + lane];
            unsigned int u6 = hsw[(size_t)s6 * 64 + lane];
            unsigned int u7 = hsw[(size_t)s7 * 64 + lane];
            ax += bflo(u0); ay += bfhi(u0);
            ax += bflo(u1); ay += bfhi(u1);
            ax += bflo(u2); ay += bfhi(u2);
            ax += bflo(u3); ay += bfhi(u3);
            ax += bflo(u4); ay += bfhi(u4);
            ax += bflo(u5); ay += bfhi(u5);
            ax += bflo(u6); ay += bfhi(u6);
            ax += bflo(u7); ay += bfhi(u7);
        }
        for (; i + 2 <= m; i += 2) {
            int s0 = __shfl(idx, i, 64), s1 = __shfl(idx, i + 1, 64);
            unsigned int u0 = hsw[(size_t)s0 * 64 + lane];
            unsigned int u1 = hsw[(size_t)s1 * 64 + lane];
            ax += bflo(u0); ay += bfhi(u0);
            ax += bflo(u1); ay += bfhi(u1);
        }
        for (; i < m; ++i) {
            int s = __shfl(idx, i, 64);
            unsigned int u = hsw[(size_t)s * 64 + lane];
            ax += bflo(u); ay += bfhi(u);
        }
    }
    const float dn = dinv[n];
    const float2 bi = *(const float2*)(bias + lane * 2);
    const float2 bm = *(const float2*)(bmat + (size_t)n * 128 + lane * 2);
    float vx = bm.x + ax * dn + bi.x;
    float vy = bm.y + ay * dn + bi.y;
    float nx = 1.0f / (1.0f + __expf(-vx));
    float ny = 1.0f / (1.0f + __expf(-vy));
    *(float2*)(out_nh + (size_t)n * 128 + lane * 2) = make_float2(nx, ny);
    ((unsigned int*)nh16)[(size_t)n * 64 + lane] =
        (unsigned int)f2bf(nx) | ((unsigned int)f2bf(ny) << 16);
}

// GEMM2: o[r][c] = cmat[r][c] + sum_h nh[r][h] * V[h][c], K=128.
__global__ __launch_bounds__(256) void gemm2_mfma_kernel(
    const unsigned short* __restrict__ nh16, const unsigned short* __restrict__ Vt,
    const float* __restrict__ cmat, float* __restrict__ o, int N)
{
    const int lane = threadIdx.x & 63;
    const int wave = threadIdx.x >> 6;
    const int i16  = lane & 15;
    const int kg   = lane >> 4;
    const int koff = kg * 8;
    const int wrow0 = blockIdx.x * 128 + wave * 32;

    f32x4 acc[2][8];
#pragma unroll
    for (int m = 0; m < 2; ++m)
#pragma unroll
        for (int n = 0; n < 8; ++n) acc[m][n] = (f32x4){0.f, 0.f, 0.f, 0.f};

    int r[2], rl[2];
#pragma unroll
    for (int m = 0; m < 2; ++m) {
        r[m]  = wrow0 + m * 16 + i16;
        rl[m] = r[m] < N ? r[m] : N - 1;
    }

#pragma unroll
    for (int ks = 0; ks < 4; ++ks) {
        const int k0 = ks * 32;
        bf16x8 xf[2];
#pragma unroll
        for (int m = 0; m < 2; ++m)
            xf[m] = *(const bf16x8*)(nh16 + (size_t)rl[m] * 128 + k0 + koff);
#pragma unroll
        for (int n = 0; n < 8; ++n) {
            bf16x8 wf = *(const bf16x8*)(Vt + (size_t)(n * 16 + i16) * 128 + k0 + koff);
            acc[0][n] = __builtin_amdgcn_mfma_f32_16x16x32_bf16(wf, xf[0], acc[0][n], 0, 0, 0);
            acc[1][n] = __builtin_amdgcn_mfma_f32_16x16x32_bf16(wf, xf[1], acc[1][n], 0, 0, 0);
        }
    }

#pragma unroll
    for (int m = 0; m < 2; ++m) {
        if (r[m] < N) {
            const float* crow = cmat + (size_t)r[m] * 128;
            float* orow = o + (size_t)r[m] * 128;
#pragma unroll
            for (int n = 0; n < 8; ++n) {
                const int c0 = n * 16 + kg * 4;
                float4 c = *(const float4*)(crow + c0);
                float4 w = make_float4(acc[m][n][0] + c.x, acc[m][n][1] + c.y,
                                       acc[m][n][2] + c.z, acc[m][n][3] + c.w);
                *(float4*)(orow + c0) = w;
            }
        }
    }
}

extern "C" void kernel_launch(void* const* d_in, const int* in_sizes, int n_in,
                              void* d_out, int out_size, void* d_ws, size_t ws_size,
                              hipStream_t stream) {
    const float* x      = (const float*)d_in[0];
    const float* hidden = (const float*)d_in[1];
    const float* W      = (const float*)d_in[2];
    const float* bias   = (const float*)d_in[3];
    const float* bmat   = (const float*)d_in[4];
    const float* V      = (const float*)d_in[5];
    const float* cmat   = (const float*)d_in[6];
    const void*  eraw   = d_in[7];

    const int H = in_sizes[3];                 // 128
    const int F = in_sizes[5] / H;             // 128
    const int N = in_sizes[0] / F;             // 100000
    const long long twoE = in_sizes[7];
    const long long E    = twoE / 2;
    const int nbkt = (N + 511) >> 9;           // 196 (requires N <= 131072)

    // ---- workspace layout ----
    char* p = (char*)d_ws;
    int* flag = (int*)p;                          p += 256;
    unsigned int* bucket_cnt = (unsigned int*)p;  p += 1024;   // [256]
    unsigned int* bucket_cursor = (unsigned int*)p; p += 1024; // [256], contiguous w/ cnt
    unsigned int* bucket_base = (unsigned int*)p; p += 2048;   // [nbkt+1]
    unsigned int* off    = (unsigned int*)p;      p += (size_t)N * 4;
    unsigned int* degcnt = (unsigned int*)p;      p += (size_t)N * 4;
    float* dinv          = (float*)p;             p += (size_t)N * 4;
    unsigned short* Wt   = (unsigned short*)p;    p += 256 * 128 * 2;
    unsigned short* Vt   = (unsigned short*)p;    p += 128 * 128 * 2;
    uint2* recs          = (uint2*)p;             p += (size_t)E * 8;
    int* csr_src         = (int*)p;               p += (size_t)E * 4;
    unsigned short* hs16 = (unsigned short*)p;    p += (size_t)N * H * 2;
    unsigned short* nh16 = (unsigned short*)p;    p += (size_t)N * H * 2;

    float* out_o  = (float*)d_out;
    float* out_nh = (float*)d_out + (size_t)N * F;

    // 0. zero bucket_cnt + bucket_cursor (contiguous 512 words)
    zero_small_kernel<<<2, 256, 0, stream>>>(bucket_cnt, 512);
    // 1. dtype detect
    detect_dtype_kernel<<<1, 256, 0, stream>>>((const unsigned int*)eraw, flag);
    // 2. bucket counts
    bucket_count_kernel<<<(unsigned)((E + 8191) / 8192), 256, 0, stream>>>(
        eraw, flag, bucket_cnt, E, N);
    // 3. scan -> bucket_base
    bucket_scan_kernel<<<1, 256, 0, stream>>>(bucket_cnt, bucket_base, nbkt, (unsigned)E);
    // 4. partition into bucket regions
    partition_kernel<<<(unsigned)((E + 4095) / 4096), 256, 0, stream>>>(
        eraw, flag, bucket_base, bucket_cursor, recs, E, N);
    // 5. per-bucket CSR fill + off/degcnt/dinv
    bucket_fill_kernel<<<nbkt, 256, 0, stream>>>(recs, bucket_base, off, degcnt,
                                                 dinv, csr_src, N);
    // 6. transposed bf16 weights
    prep_wt_kernel<<<192, 256, 0, stream>>>(W, V, Wt, Vt);
    // 7. GEMM1 (MFMA, scaled by dinv)
    gemm1_mfma_kernel<<<(N + 127) / 128, 256, 0, stream>>>(x, hidden, Wt, dinv, hs16, N);
    // 8. aggregate + sigmoid -> new_hidden (f32) + nh16 (bf16)
    aggregate_kernel<<<(N + 3) / 4, 256, 0, stream>>>(hs16, csr_src, off, degcnt, dinv,
                                                      bmat, bias, out_nh, nh16, N);
    // 9. GEMM2 -> o
    gemm2_mfma_kernel<<<(N + 127) / 128, 256, 0, stream>>>(nh16, Vt, cmat, out_o, N);
}